// Round 6
// baseline (37.001 us; speedup 1.0000x reference)
//
#include <hip/hip_runtime.h>

// Shapes (fixed by the problem)
#define B_   32
#define N_   64
#define C_   256
#define H_   256
#define L_   16
#define NPAIR 4096

typedef __attribute__((ext_vector_type(8))) _Float16  f16x8;
typedef __attribute__((ext_vector_type(4))) float     f32x4;

static __device__ __forceinline__ unsigned short f2h(float f) {
    return __builtin_bit_cast(unsigned short, (_Float16)f);   // v_cvt_f16_f32 (RNE)
}

// Fragment-linear layouts (elem offsets):
//  srcf (per b): ((( (n>>4)*8 + (c>>5) )*4 + ((c>>3)&3) )*16 + (n&15))*8 + (c&7)
//  w1h/w1l:      ((( (h>>4)*8 + (c>>5) )*4 + ((c>>3)&3) )*16 + (h&15))*8 + (c&7)
//  coef:         ((( (p>>4)*2 + (n>>5) )*4 + ((n>>3)&3) )*16 + (p&15))*8 + (n&7)
// -> every wave frag load is 64 lanes x 16B CONTIGUOUS (coalesced / bank-free).

// ---------------------------------------------------------------------------
// kPrep: blocks [0,256)  : src  -> srcf  f16 frag-linear (8 elems/thread)
//        blocks [256,288): W1   -> w1h/w1l split-f16 frag-linear
//        blocks [288,1312): spd -> coef  f16 frag-linear
// ---------------------------------------------------------------------------
__global__ __launch_bounds__(256) void kPrep(const float* __restrict__ src,
                                             const float* __restrict__ W1,
                                             const int*   __restrict__ spd,
                                             const int*   __restrict__ spd_len,
                                             unsigned short* __restrict__ srcf,
                                             unsigned short* __restrict__ w1h,
                                             unsigned short* __restrict__ w1l,
                                             unsigned short* __restrict__ coef) {
    const int bid = blockIdx.x, tid = threadIdx.x;
    if (bid < 256) {
        const int t = bid * 256 + tid;           // (b, n, c8): b*2048 + n*32 + c8
        const int b = t >> 11, rem = t & 2047, n = rem >> 5, c = (rem & 31) * 8;
        const float* p = src + ((b * 64 + n) * 256 + c);
        float4 q0 = *(const float4*)p, q1 = *(const float4*)(p + 4);
        float vv[8] = {q0.x,q0.y,q0.z,q0.w,q1.x,q1.y,q1.z,q1.w};
        f16x8 v;
        #pragma unroll
        for (int j = 0; j < 8; ++j) v[j] = (_Float16)vv[j];
        const int off = b * 16384 +
            ((((n >> 4) * 8 + (c >> 5)) * 4 + ((c >> 3) & 3)) * 16 + (n & 15)) * 8;
        *(f16x8*)(srcf + off) = v;
    } else if (bid < 288) {
        const int t = (bid - 256) * 256 + tid;   // h*32 + c8
        const int h = t >> 5, c = (t & 31) * 8;
        const float* p = W1 + h * 256 + c;
        float4 q0 = *(const float4*)p, q1 = *(const float4*)(p + 4);
        float vv[8] = {q0.x,q0.y,q0.z,q0.w,q1.x,q1.y,q1.z,q1.w};
        f16x8 vh, vl;
        #pragma unroll
        for (int j = 0; j < 8; ++j) {
            _Float16 hi = (_Float16)vv[j];
            vh[j] = hi;
            vl[j] = (_Float16)(vv[j] - (float)hi);
        }
        const int off = ((((h >> 4) * 8 + (c >> 5)) * 4 + ((c >> 3) & 3)) * 16 + (h & 15)) * 8;
        *(f16x8*)(w1h + off) = vh;
        *(f16x8*)(w1l + off) = vl;
    } else {
        const int t    = (bid - 288) * 256 + tid;    // [0, 4096*64)
        const int pair = t >> 6;
        const int n    = t & 63;
        const int len  = spd_len[pair];
        const int* row = spd + pair * L_;
        int a = 0;
        for (int k = 0; k + 1 < len; ++k)
            a += (row[k+1] == n) - (row[k] == n);
        const int off = ((((pair >> 4) * 2 + (n >> 5)) * 4 + ((n >> 3) & 3)) * 16 + (pair & 15)) * 8 + (n & 7);
        coef[off] = f2h((float)a);                   // exact, |a| <= 15
    }
}

// ---------------------------------------------------------------------------
// kMain: grid 512 = (b:32) x (pg:16 groups of 256 pairs), 256 threads (4 waves).
// LDS 66KB -> 2 blocks/CU (independent blocks overlap phases/barriers).
// Phase Y: y[b] = W1*src^T, 2-pass split-f16 (hi+lo), frags pre-converted.
//   wave w owns h-tiles w*4..w*4+3 (x 4 n-tiles x 8 kc x 2 MFMA = 256 MFMA).
//   D: col(l15)=h, row(lg*4+r)=n -> write ylds fp16 swizzled (h-row 128B,
//   byte = h*128 + ((n*2) ^ ((h&7)<<4))).
// Phase C: wave (ps=w>>1, hh=w&1): 128 pairs x 128 h; bfrag persistent from
//   ylds; af (coef) straight from global (L2-hot, frag-linear); PReLU + W2
//   dot + 16-lane shuffle reduce -> red -> out.
// ---------------------------------------------------------------------------
__global__ __launch_bounds__(256, 2)
void kMain(const unsigned short* __restrict__ srcf,
           const unsigned short* __restrict__ w1h,
           const unsigned short* __restrict__ w1l,
           const unsigned short* __restrict__ coef,
           const float* __restrict__ W2,
           const float* __restrict__ prelu_a,
           float* __restrict__ out) {
    __shared__ unsigned short sfl[16384];     // 32KB frag-linear src[b]
    __shared__ char  ylds[32768];             // 32KB y[b] fp16 swizzled
    __shared__ float red[2][256];             // 2KB

    const int bid = blockIdx.x;
    const int b = bid >> 4, pg = bid & 15;
    const int tid = threadIdx.x, lane = tid & 63, w = tid >> 6;
    const int l15 = lane & 15, lg = lane >> 4;

    // ---- stage src frags (linear 32KB copy)
    {
        const int4* s4 = (const int4*)(srcf + b * 16384);
        int4* d4 = (int4*)sfl;
        #pragma unroll
        for (int i = 0; i < 8; ++i) d4[i * 256 + tid] = s4[i * 256 + tid];
    }
    __syncthreads();

    // ---- phase Y
    {
        f32x4 acc[4][4];
        #pragma unroll
        for (int ht = 0; ht < 4; ++ht)
            #pragma unroll
            for (int nt = 0; nt < 4; ++nt) acc[ht][nt] = (f32x4){0.f,0.f,0.f,0.f};

        #pragma unroll 2
        for (int kc = 0; kc < 8; ++kc) {
            f16x8 sa[4];
            #pragma unroll
            for (int nt = 0; nt < 4; ++nt)
                sa[nt] = *(const f16x8*)(sfl + (((nt * 8 + kc) * 4 + lg) * 16 + l15) * 8);
            #pragma unroll
            for (int ht = 0; ht < 4; ++ht) {
                const int HT = w * 4 + ht;
                const int fo = (((HT * 8 + kc) * 4 + lg) * 16 + l15) * 8;
                f16x8 bh = *(const f16x8*)(w1h + fo);
                f16x8 bl = *(const f16x8*)(w1l + fo);
                #pragma unroll
                for (int nt = 0; nt < 4; ++nt) {
                    acc[ht][nt] = __builtin_amdgcn_mfma_f32_16x16x32_f16(sa[nt], bh, acc[ht][nt], 0, 0, 0);
                    acc[ht][nt] = __builtin_amdgcn_mfma_f32_16x16x32_f16(sa[nt], bl, acc[ht][nt], 0, 0, 0);
                }
            }
        }

        // write y tiles: lane holds 4 consecutive n at fixed h
        #pragma unroll
        for (int ht = 0; ht < 4; ++ht) {
            const int h = (w * 4 + ht) * 16 + l15;
            #pragma unroll
            for (int nt = 0; nt < 4; ++nt) {
                const int n0 = nt * 16 + lg * 4;
                unsigned pk[2];
                pk[0] = (unsigned)f2h(acc[ht][nt][0]) | ((unsigned)f2h(acc[ht][nt][1]) << 16);
                pk[1] = (unsigned)f2h(acc[ht][nt][2]) | ((unsigned)f2h(acc[ht][nt][3]) << 16);
                const unsigned off = (unsigned)(h * 128) +
                    (((unsigned)(n0 * 2)) ^ ((unsigned)(h & 7) << 4));
                *(int2*)(ylds + off) = *(int2*)pk;
            }
        }
    }
    __syncthreads();

    // ---- phase C
    {
        const int ps = w >> 1, hh = w & 1;

        f16x8 bfrag[8][2];
        #pragma unroll
        for (int nt = 0; nt < 8; ++nt) {
            const int h = hh * 128 + nt * 16 + l15;
            #pragma unroll
            for (int ks = 0; ks < 2; ++ks) {
                const unsigned off = (unsigned)(h * 128) +
                    (((unsigned)(lg * 16 + ks * 64)) ^ ((unsigned)(h & 7) << 4));
                bfrag[nt][ks] = *(const f16x8*)(ylds + off);
            }
        }

        float w2v[8];
        #pragma unroll
        for (int nt = 0; nt < 8; ++nt) w2v[nt] = W2[hh * 128 + nt * 16 + l15];
        const float a = *prelu_a;

        for (int pt = 0; pt < 8; ++pt) {
            const int tl  = ps * 8 + pt;              // pair-tile within block
            const int ptg = pg * 16 + tl;             // global pair-tile

            f16x8 af[2];
            #pragma unroll
            for (int ks = 0; ks < 2; ++ks)
                af[ks] = *(const f16x8*)(coef + (((ptg * 2 + ks) * 4 + lg) * 16 + l15) * 8);

            f32x4 pacc[8];
            #pragma unroll
            for (int nt = 0; nt < 8; ++nt) pacc[nt] = (f32x4){0.f,0.f,0.f,0.f};
            #pragma unroll
            for (int ks = 0; ks < 2; ++ks)
                #pragma unroll
                for (int nt = 0; nt < 8; ++nt)
                    pacc[nt] = __builtin_amdgcn_mfma_f32_16x16x32_f16(af[ks], bfrag[nt][ks], pacc[nt], 0, 0, 0);

            float s[4] = {0.f, 0.f, 0.f, 0.f};
            #pragma unroll
            for (int nt = 0; nt < 8; ++nt)
                #pragma unroll
                for (int r = 0; r < 4; ++r) {
                    float v = pacc[nt][r];
                    v = fmaxf(v, 0.f) + a * fminf(v, 0.f);
                    s[r] += v * w2v[nt];
                }
            #pragma unroll
            for (int m = 1; m < 16; m <<= 1)
                #pragma unroll
                for (int r = 0; r < 4; ++r) s[r] += __shfl_xor(s[r], m);

            if (l15 == 0) {
                #pragma unroll
                for (int r = 0; r < 4; ++r)
                    red[hh][tl * 16 + lg * 4 + r] = s[r];
            }
        }
    }
    __syncthreads();
    out[b * NPAIR + pg * 256 + tid] = red[0][tid] + red[1][tid];
}

// ---------------------------------------------------------------------------
extern "C" void kernel_launch(void* const* d_in, const int* in_sizes, int n_in,
                              void* d_out, int out_size, void* d_ws, size_t ws_size,
                              hipStream_t stream) {
    const float* src     = (const float*)d_in[0];
    const float* W1      = (const float*)d_in[1];
    const float* W2      = (const float*)d_in[2];
    const float* prelu_a = (const float*)d_in[3];
    const int*   spd     = (const int*)d_in[4];
    const int*   spd_len = (const int*)d_in[5];
    float* out = (float*)d_out;

    unsigned short* srcf = (unsigned short*)d_ws;     // 524288 elems (1 MB)
    unsigned short* w1h  = srcf + 524288;             // 65536 (128 KB)
    unsigned short* w1l  = w1h + 65536;               // 65536 (128 KB)
    unsigned short* coef = w1l + 65536;               // 262144 (512 KB)

    kPrep<<<1312, 256, 0, stream>>>(src, W1, spd, spd_len, srcf, w1h, w1l, coef);
    kMain<<<512,  256, 0, stream>>>(srcf, w1h, w1l, coef, W2, prelu_a, out);
}

// Round 8
// 19.306 us; speedup vs baseline: 1.9166x; 1.9166x over previous
//
#include <hip/hip_runtime.h>

// Shapes (fixed by the problem)
#define B_   32
#define N_   64
#define C_   256
#define H_   256
#define L_   16
#define NPAIR 4096
#define PPB   512            // pairs per block

typedef __attribute__((ext_vector_type(8))) _Float16 f16x8;
typedef __attribute__((ext_vector_type(2))) _Float16 f16x2;
typedef __attribute__((ext_vector_type(4))) float    f32x4;

static __device__ __forceinline__ unsigned short f2h_u(float f) {
    return __builtin_bit_cast(unsigned short, (_Float16)f);   // v_cvt_f16_f32 RNE
}

// KEY IDENTITY: the reference coef sum telescopes:
//   coef[p,n] = [spd[p,len-1]==n] - [spd[p,0]==n]
// so out[b,p] = sum_h W2[h] * prelu( y[b,e,h] - y[b,h0,h] ),  y = src @ W1^T.
//
// Single kernel, grid 256 = (b:32) x (pg:8 x 512 pairs), 512 threads (8 waves).
// LDS: sfl 32KB  src[b] f16 [n][c] rows 512B, 16B-granule XOR (n&7)<<4
//      yl  32KB  y[b]  f16 [n][h] rows 512B, 32B-granule XOR (n&7)<<5
//      w2l 512B  W2 f16 linear
__global__ __launch_bounds__(512, 2)
void kFused(const float* __restrict__ src,
            const float* __restrict__ W1,
            const float* __restrict__ W2,
            const float* __restrict__ prelu_a,
            const int*   __restrict__ spd,
            const int*   __restrict__ spd_len,
            float*       __restrict__ out) {
    __shared__ char sfl[32768];
    __shared__ char yl[32768];
    __shared__ char w2l[512];

    const int bid = blockIdx.x, b = bid >> 3, pg = bid & 7;
    const int tid = threadIdx.x, lane = tid & 63, w = tid >> 6;
    const int l15 = lane & 15, lg = lane >> 4;

    // issue stage-2 index loads early (latency hidden under phase Y)
    const int gp  = pg * PPB + tid;                 // this thread's pair
    const int len = spd_len[gp];
    const int n_h = spd[gp * L_];                   // h0 = spd[p,0]
    const int n_e = spd[gp * L_ + len - 1];         // e  = spd[p,len-1]

    // W2 -> LDS f16
    if (tid < 32) {
        float4 q0 = *(const float4*)(W2 + tid * 8);
        float4 q1 = *(const float4*)(W2 + tid * 8 + 4);
        unsigned pk0 = f2h_u(q0.x) | ((unsigned)f2h_u(q0.y) << 16);
        unsigned pk1 = f2h_u(q0.z) | ((unsigned)f2h_u(q0.w) << 16);
        unsigned pk2 = f2h_u(q1.x) | ((unsigned)f2h_u(q1.y) << 16);
        unsigned pk3 = f2h_u(q1.z) | ((unsigned)f2h_u(q1.w) << 16);
        int4 v; v.x = pk0; v.y = pk1; v.z = pk2; v.w = pk3;
        *(int4*)(w2l + tid * 16) = v;
    }

    // ---- stage src[b] -> LDS f16 (fully coalesced global; conflict-free LDS)
    {
        const float4* sb = (const float4*)(src + (size_t)b * (N_ * C_));
        #pragma unroll
        for (int i = 0; i < 8; ++i) {
            const int f = i * 512 + tid;            // flat float4 index
            const int n = f >> 6, c4 = f & 63;      // row n, c4-th float4
            float4 q = sb[f];
            unsigned pk0 = f2h_u(q.x) | ((unsigned)f2h_u(q.y) << 16);
            unsigned pk1 = f2h_u(q.z) | ((unsigned)f2h_u(q.w) << 16);
            int2 v; v.x = (int)pk0; v.y = (int)pk1;
            const unsigned off = (unsigned)(n * 512) +
                (((unsigned)(c4 * 8)) ^ ((unsigned)(n & 7) << 4));
            *(int2*)(sfl + off) = v;
        }
    }
    __syncthreads();

    // ---- phase Y: y[n][h] = sum_c src[n][c]*W1[h][c]; 2-pass split-f16 W1.
    // wave w owns h-tiles {2w, 2w+1}. A=W1 (rows h), B=src (cols n).
    // D: col(l15)=n, row(lg*4+r)=h-sub -> 4 consecutive h per lane = b64 write.
    {
        f32x4 acc[2][4];
        #pragma unroll
        for (int i2 = 0; i2 < 2; ++i2)
            #pragma unroll
            for (int nt = 0; nt < 4; ++nt) acc[i2][nt] = (f32x4){0.f,0.f,0.f,0.f};

        #pragma unroll
        for (int kc = 0; kc < 8; ++kc) {
            f16x8 sa[4];
            #pragma unroll
            for (int nt = 0; nt < 4; ++nt) {
                const int n = nt * 16 + l15;
                const unsigned off = (unsigned)(n * 512) +
                    (((unsigned)(kc * 64 + lg * 16)) ^ ((unsigned)(n & 7) << 4));
                sa[nt] = *(const f16x8*)(sfl + off);
            }
            #pragma unroll
            for (int i2 = 0; i2 < 2; ++i2) {
                const int h = (w * 2 + i2) * 16 + l15;
                const float* wp = W1 + h * C_ + kc * 32 + lg * 8;
                float4 q0 = *(const float4*)wp;
                float4 q1 = *(const float4*)(wp + 4);
                float vv[8] = {q0.x,q0.y,q0.z,q0.w,q1.x,q1.y,q1.z,q1.w};
                f16x8 wh, wl;
                #pragma unroll
                for (int j = 0; j < 8; ++j) {
                    _Float16 hi = (_Float16)vv[j];
                    wh[j] = hi;
                    wl[j] = (_Float16)(vv[j] - (float)hi);
                }
                #pragma unroll
                for (int nt = 0; nt < 4; ++nt) {
                    acc[i2][nt] = __builtin_amdgcn_mfma_f32_16x16x32_f16(wh, sa[nt], acc[i2][nt], 0, 0, 0);
                    acc[i2][nt] = __builtin_amdgcn_mfma_f32_16x16x32_f16(wl, sa[nt], acc[i2][nt], 0, 0, 0);
                }
            }
        }

        // write y: lane holds h = ht*16+lg*4..+3 at n = nt*16+l15
        #pragma unroll
        for (int i2 = 0; i2 < 2; ++i2) {
            const int ht = w * 2 + i2;
            #pragma unroll
            for (int nt = 0; nt < 4; ++nt) {
                const int n = nt * 16 + l15;
                unsigned pk0 = f2h_u(acc[i2][nt][0]) | ((unsigned)f2h_u(acc[i2][nt][1]) << 16);
                unsigned pk1 = f2h_u(acc[i2][nt][2]) | ((unsigned)f2h_u(acc[i2][nt][3]) << 16);
                int2 v; v.x = (int)pk0; v.y = (int)pk1;
                const unsigned off = (unsigned)(n * 512) +
                    (((unsigned)(ht * 32)) ^ ((unsigned)(n & 7) << 5)) + (unsigned)(lg * 8);
                *(int2*)(yl + off) = v;
            }
        }
    }
    __syncthreads();

    // ---- stage 2: out[b,gp] = sum_h w2[h]*prelu(y[e][h]-y[h0][h]).
    // Thread owns its pair fully: no shuffles, no cross-lane reduce.
    {
        const float a = *prelu_a;
        float accP = 0.f, accN = 0.f;
        const char* re = yl + n_e * 512;
        const char* rh = yl + n_h * 512;
        const unsigned se = ((unsigned)(n_e & 7)) << 5;
        const unsigned sh = ((unsigned)(n_h & 7)) << 5;
        #pragma unroll 4
        for (int c = 0; c < 32; ++c) {
            f16x8 ye  = *(const f16x8*)(re + (((unsigned)(c * 16)) ^ se));
            f16x8 yh  = *(const f16x8*)(rh + (((unsigned)(c * 16)) ^ sh));
            f16x8 w2c = *(const f16x8*)(w2l + c * 16);
            f16x8 d = ye - yh;                        // v_pk_add_f16 (neg)
            f16x8 z = {};
            f16x8 pos = __builtin_elementwise_max(d, z);   // v_pk_max_f16
            f16x8 neg = __builtin_elementwise_min(d, z);   // v_pk_min_f16
            const int4 pi = __builtin_bit_cast(int4, pos);
            const int4 ni = __builtin_bit_cast(int4, neg);
            const int4 wi = __builtin_bit_cast(int4, w2c);
            const int pa[4] = {pi.x, pi.y, pi.z, pi.w};
            const int na[4] = {ni.x, ni.y, ni.z, ni.w};
            const int wa[4] = {wi.x, wi.y, wi.z, wi.w};
            #pragma unroll
            for (int i = 0; i < 4; ++i) {
                f16x2 p2 = __builtin_bit_cast(f16x2, pa[i]);
                f16x2 n2 = __builtin_bit_cast(f16x2, na[i]);
                f16x2 w2 = __builtin_bit_cast(f16x2, wa[i]);
#if __has_builtin(__builtin_amdgcn_fdot2)
                accP = __builtin_amdgcn_fdot2(p2, w2, accP, false);
                accN = __builtin_amdgcn_fdot2(n2, w2, accN, false);
#else
                accP += (float)p2[0]*(float)w2[0] + (float)p2[1]*(float)w2[1];
                accN += (float)n2[0]*(float)w2[0] + (float)n2[1]*(float)w2[1];
#endif
            }
        }
        out[b * NPAIR + gp] = accP + a * accN;   // prelu = max(x,0) + a*min(x,0)
    }
}

// ---------------------------------------------------------------------------
extern "C" void kernel_launch(void* const* d_in, const int* in_sizes, int n_in,
                              void* d_out, int out_size, void* d_ws, size_t ws_size,
                              hipStream_t stream) {
    const float* src     = (const float*)d_in[0];
    const float* W1      = (const float*)d_in[1];
    const float* W2      = (const float*)d_in[2];
    const float* prelu_a = (const float*)d_in[3];
    const int*   spd     = (const int*)d_in[4];
    const int*   spd_len = (const int*)d_in[5];
    float* out = (float*)d_out;

    kFused<<<256, 512, 0, stream>>>(src, W1, W2, prelu_a, spd, spd_len, out);
}